// Round 1
// baseline (127.096 us; speedup 1.0000x reference)
//
#include <hip/hip_runtime.h>
#include <hip/hip_fp16.h>

// GCN-style symmetric-normalized CSR aggregation.
// out[d][f] = sum_e feat[col_idx[e]][f] * rsqrt(deg[d]*deg[col_idx[e]])
//
// Round-7 theory: neither HBM bytes (r5) nor VMEM inst count (r6) fully
// explains 130 us. Remaining cost model: per-row fixed overhead + serial
// latency chains. Avg degree ~16 (exponential), so each wave previously did
// ~2 gather insts of real work but paid a full 64-wide col_idx load (75%
// lanes wasted), a 3-level x8 shuffle reduce, and a 4-deep dependent memory
// chain with only ~2 loads in flight.
//
// Change: TWO destination rows per wave. Each 32-lane half owns one row
// (4 slots x 8 lanes; one gather inst still covers 8 edges at 16B/lane).
//  - wave count 100K -> 50K; per-row fixed costs halved
//  - one col_idx load serves both rows (32 useful idx/half, not 16/64)
//  - two rows' gathers are independent -> 2x per-wave MLP
//  - reduce drops to 2 shuffle levels
//  - col_idx loads nontemporal (protect fp16 feat table in L2)

typedef float    v4f __attribute__((ext_vector_type(4)));
typedef unsigned v4u __attribute__((ext_vector_type(4)));

// ---------------- pass 1: fold rsqrt(deg[src]) and convert to fp16 ----------
__global__ __launch_bounds__(256) void conv_fold(
    const float4* __restrict__ in, const float* __restrict__ deg,
    uint2* __restrict__ out, int n4)
{
    const int i = blockIdx.x * blockDim.x + threadIdx.x;
    if (i >= n4) return;
    const float w = rsqrtf(deg[i >> 4]);   // 16 float4 per 64-float row
    const float4 f = in[i];
    union { __half2 h; unsigned u; } a, b;
    a.h = __floats2half2_rn(f.x * w, f.y * w);
    b.h = __floats2half2_rn(f.z * w, f.w * w);
    out[i] = make_uint2(a.u, b.u);
}

// ---------------- pass 2: gather + aggregate, 2 rows per wave ---------------
__global__ __launch_bounds__(256) void gcn_gather2(
    const int* __restrict__ row_ptr,
    const int* __restrict__ col_idx,
    const unsigned* __restrict__ feath,   // fp16, weight-folded, 128B rows
    const float* __restrict__ deg,
    float* __restrict__ out,
    int n_nodes)
{
    const int gtid = blockIdx.x * blockDim.x + threadIdx.x;
    const int wave = gtid >> 6;
    if (wave * 2 >= n_nodes) return;
    const int lane = threadIdx.x & 63;
    const int half = lane >> 5;        // which of the 2 rows
    const int l32  = lane & 31;
    const int slot = l32 >> 3;         // edge slot 0..3 within the half
    const int k    = lane & 7;         // 16B chunk within 128B fp16 row
    const int kb   = k << 4;

    const int row   = min(wave * 2 + half, n_nodes - 1);
    const int start = row_ptr[row];
    const int end   = row_ptr[row + 1];
    const int deg_r = end - start;
    // wave-uniform trip count: no divergence between the two halves
    const int degM  = max(deg_r, __shfl_xor(deg_r, 32));
    const int last  = (deg_r > 0) ? (end - 1) : 0;  // safe clamp for col load
    const char* hbase = (const char*)feath;
    const int hb = half << 5;

    float acc[8] = {0.f, 0.f, 0.f, 0.f, 0.f, 0.f, 0.f, 0.f};

    for (int base = 0; base < degM; base += 32) {
        // 1 coalesced inst: 32 edge indices per half (tail lanes clamp-dup).
        const int cidx = __builtin_nontemporal_load(
            &col_idx[min(start + base + l32, last)]);
        const int nrem  = min(deg_r - base, 32);   // per-half, may be <= 0
        const int nremM = min(degM  - base, 32);   // uniform, >= 1
        const int ntM   = (nremM + 3) >> 2;        // 4-edge steps per half
        const int nc    = max(nrem, 1) - 1;        // clamp index
        for (int t = 0; t < ntM; t += 2) {
            const int j0 = t * 4 + slot;
            const int j1 = j0 + 4;
            const int s0 = __shfl(cidx, hb + min(j0, nc));
            const int s1 = __shfl(cidx, hb + min(j1, nc));
            // 2 insts cover 16 edges (8 rows each, 16B/lane), both halves.
            const v4u q0 = *reinterpret_cast<const v4u*>(hbase + (((unsigned)s0) << 7) + kb);
            const v4u q1 = *reinterpret_cast<const v4u*>(hbase + (((unsigned)s1) << 7) + kb);
            const float w0 = (j0 < nrem) ? 1.f : 0.f;
            const float w1 = (j1 < nrem) ? 1.f : 0.f;
#pragma unroll
            for (int p = 0; p < 4; ++p) {
                union { unsigned u; __half2 h; } c0, c1;
                c0.u = q0[p]; c1.u = q1[p];
                const float2 f0 = __half22float2(c0.h);
                const float2 f1 = __half22float2(c1.h);
                acc[2 * p]     += w0 * f0.x + w1 * f1.x;
                acc[2 * p + 1] += w0 * f0.y + w1 * f1.y;
            }
        }
    }

    // Reduce across the 4 slots of each half (lane bits 3,4).
#pragma unroll
    for (int m = 8; m <= 16; m <<= 1) {
#pragma unroll
        for (int i = 0; i < 8; ++i) acc[i] += __shfl_xor(acc[i], m);
    }

    if (slot == 0) {
        const float dinv = rsqrtf(deg[row]);   // deg clamped >= 1 by setup
        v4f lo = {acc[0] * dinv, acc[1] * dinv, acc[2] * dinv, acc[3] * dinv};
        v4f hi = {acc[4] * dinv, acc[5] * dinv, acc[6] * dinv, acc[7] * dinv};
        char* po = (char*)out + (((unsigned)row) << 8) + (k << 5);
        __builtin_nontemporal_store(lo, reinterpret_cast<v4f*>(po));
        __builtin_nontemporal_store(hi, reinterpret_cast<v4f*>(po + 16));
    }
}

// ---------------- fallback: fp32 gather (round-3 kernel) --------------------
__global__ __launch_bounds__(256) void gcn_csr_agg_f(
    const int* __restrict__ row_ptr,
    const int* __restrict__ col_idx,
    const float* __restrict__ feat,
    const float* __restrict__ deg,
    float* __restrict__ out,
    int n_nodes)
{
    const int gtid = blockIdx.x * blockDim.x + threadIdx.x;
    const int row  = gtid >> 6;
    if (row >= n_nodes) return;
    const int lane = threadIdx.x & 63;
    const int sub  = lane >> 4;
    const int fbyte = (lane & 15) << 4;

    const int start = row_ptr[row];
    const int end   = row_ptr[row + 1];
    const int last  = end - 1;
    const float dinv = rsqrtf(deg[row]);
    const char* fbase = (const char*)feat;

    v4f acc = {0.f, 0.f, 0.f, 0.f};

    for (int eb = start; eb < end; eb += 16) {
        int e[4]; int s[4]; float d[4]; v4f f[4];
#pragma unroll
        for (int u = 0; u < 4; ++u) {
            e[u] = eb + sub + 4 * u;
            const int c = min(e[u], last);
            s[u] = col_idx[c];
        }
#pragma unroll
        for (int u = 0; u < 4; ++u) {
            d[u] = deg[s[u]];
            const unsigned off = ((unsigned)s[u] << 8) + fbyte;
            f[u] = *reinterpret_cast<const v4f*>(fbase + off);
        }
#pragma unroll
        for (int u = 0; u < 4; ++u) {
            const float w = (e[u] <= last) ? dinv * rsqrtf(d[u]) : 0.f;
            acc += w * f[u];
        }
    }

    acc.x += __shfl_xor(acc.x, 16); acc.y += __shfl_xor(acc.y, 16);
    acc.z += __shfl_xor(acc.z, 16); acc.w += __shfl_xor(acc.w, 16);
    acc.x += __shfl_xor(acc.x, 32); acc.y += __shfl_xor(acc.y, 32);
    acc.z += __shfl_xor(acc.z, 32); acc.w += __shfl_xor(acc.w, 32);

    if (sub == 0) {
        v4f* po = reinterpret_cast<v4f*>((char*)out + ((unsigned)row << 8) + fbyte);
        __builtin_nontemporal_store(acc, po);
    }
}

extern "C" void kernel_launch(void* const* d_in, const int* in_sizes, int n_in,
                              void* d_out, int out_size, void* d_ws, size_t ws_size,
                              hipStream_t stream) {
    const int*   row_ptr = (const int*)d_in[0];
    const int*   col_idx = (const int*)d_in[1];
    const float* feat    = (const float*)d_in[2];
    const float* deg     = (const float*)d_in[3];
    float*       out     = (float*)d_out;

    const int n_nodes = in_sizes[0] - 1;
    const int n_feat_elems = in_sizes[2];            // n_nodes * 64
    const size_t h_bytes = (size_t)n_feat_elems * 2; // fp16 copy size

    const int block = 256;

    if (ws_size >= h_bytes) {
        const int n4 = n_feat_elems >> 2;
        const int cgrid = (n4 + block - 1) / block;
        conv_fold<<<cgrid, block, 0, stream>>>(
            (const float4*)feat, deg, (uint2*)d_ws, n4);
        const long long waves = (n_nodes + 1) / 2;
        const long long threads = waves * 64;
        const int grid = (int)((threads + block - 1) / block);
        gcn_gather2<<<grid, block, 0, stream>>>(
            row_ptr, col_idx, (const unsigned*)d_ws, deg, out, n_nodes);
    } else {
        const long long threads = (long long)n_nodes * 64;
        const int grid  = (int)((threads + block - 1) / block);
        gcn_csr_agg_f<<<grid, block, 0, stream>>>(
            row_ptr, col_idx, feat, deg, out, n_nodes);
    }
}

// Round 2
// 126.523 us; speedup vs baseline: 1.0045x; 1.0045x over previous
//
#include <hip/hip_runtime.h>
#include <hip/hip_fp16.h>

// GCN-style symmetric-normalized CSR aggregation.
// out[d][f] = sum_e feat[col_idx[e]][f] * rsqrt(deg[d]*deg[col_idx[e]])
//
// Round-8 theory: gather is latency/occupancy-bound (Occ 48%, VALU 42%,
// HBM 29%, nothing saturated). 12.5K short-lived blocks (~0.7us each)
// churn through the CP; avg resident waves/SIMD ~3.8.
// Changes:
//  1. PERSISTENT waves: 2048 blocks (8/CU, resident at <=64 VGPR), each
//     wave strides over ~6 row-pairs. No churn; latency hidden by 8
//     resident waves/SIMD.
//  2. Pipeline: prefetch next pair's row_ptr/deg while gathering current.
//  3. Zero-row deskew: conv writes an all-zero fp16 row at index n_nodes;
//     tail lanes clamp col_idx to it. Inner loop loses all masking math
//     (tail gathers hit an L1-hot zero row).

typedef float    v4f __attribute__((ext_vector_type(4)));
typedef unsigned v4u __attribute__((ext_vector_type(4)));

// ---------------- pass 1: fold rsqrt(deg[src]) -> fp16 table (+ zero row) ---
__global__ __launch_bounds__(256) void conv_fold(
    const float4* __restrict__ in, const float* __restrict__ deg,
    uint2* __restrict__ out, int n4)
{
    const int i = blockIdx.x * blockDim.x + threadIdx.x;
    if (i >= n4 + 16) return;
    if (i >= n4) { out[i] = make_uint2(0u, 0u); return; }  // zero row @ n_nodes
    const float w = rsqrtf(deg[i >> 4]);   // 16 float4 per 64-float row
    const float4 f = in[i];
    union { __half2 h; unsigned u; } a, b;
    a.h = __floats2half2_rn(f.x * w, f.y * w);
    b.h = __floats2half2_rn(f.z * w, f.w * w);
    out[i] = make_uint2(a.u, b.u);
}

// ---------------- pass 2: persistent gather, 2 rows per wave ----------------
__global__ __launch_bounds__(256, 8) void gcn_gather2p(
    const int* __restrict__ row_ptr,
    const int* __restrict__ col_idx,
    const unsigned* __restrict__ feath,   // fp16, weight-folded, 128B rows
    const float* __restrict__ deg,
    float* __restrict__ out,
    int n_nodes, int n_edges)
{
    const int lane = threadIdx.x & 63;
    const int half = lane >> 5;        // which of the 2 rows
    const int l32  = lane & 31;
    const int slot = l32 >> 3;         // edge slot 0..3 within the half
    const int k    = lane & 7;         // 16B chunk within 128B fp16 row
    const int kb   = k << 4;
    const int hb   = half << 5;
    const char* hbase = (const char*)feath;
    const int Em1  = n_edges - 1;
    const int zrow = n_nodes;

    const int wid = (blockIdx.x * blockDim.x + threadIdx.x) >> 6;
    const int nw  = (gridDim.x * blockDim.x) >> 6;
    const int npairs = (n_nodes + 1) >> 1;
    if (wid >= npairs) return;

    int pair  = wid;
    int row   = min(pair * 2 + half, n_nodes - 1);
    int start = row_ptr[row];
    int end   = row_ptr[row + 1];
    float dcur = deg[row];

    for (;;) {
        // ---- prefetch next pair's bounds + deg (hidden under the gather) ---
        const int npair  = pair + nw;
        const int nrow   = min(min(npair, npairs - 1) * 2 + half, n_nodes - 1);
        const int nstart = row_ptr[nrow];
        const int nend   = row_ptr[nrow + 1];
        const float ndeg = deg[nrow];

        const int deg_r = end - start;
        const int degM  = max(deg_r, __shfl_xor(deg_r, 32));

        float acc[8] = {0.f, 0.f, 0.f, 0.f, 0.f, 0.f, 0.f, 0.f};

        for (int base = 0; base < degM; base += 32) {
            const int e = start + base + l32;
            int cidx = __builtin_nontemporal_load(&col_idx[min(e, Em1)]);
            if (e >= end) cidx = zrow;                 // tail -> zero row
            const int ntM = (min(degM - base, 32) + 3) >> 2;  // 4-edge steps
            for (int t = 0; t < ntM; t += 2) {
                const int s0 = __shfl(cidx, hb + t * 4 + slot);
                const int s1 = __shfl(cidx, hb + min(t * 4 + slot + 4, 31));
                const v4u q0 = *reinterpret_cast<const v4u*>(hbase + (((unsigned)s0) << 7) + kb);
                const v4u q1 = *reinterpret_cast<const v4u*>(hbase + (((unsigned)s1) << 7) + kb);
#pragma unroll
                for (int p = 0; p < 4; ++p) {
                    union { unsigned u; __half2 h; } c0, c1;
                    c0.u = q0[p]; c1.u = q1[p];
                    const float2 f0 = __half22float2(c0.h);
                    const float2 f1 = __half22float2(c1.h);
                    acc[2 * p]     += f0.x + f1.x;
                    acc[2 * p + 1] += f0.y + f1.y;
                }
            }
        }

        // Reduce across the 4 slots of each half (lane bits 3,4).
#pragma unroll
        for (int m = 8; m <= 16; m <<= 1) {
#pragma unroll
            for (int i = 0; i < 8; ++i) acc[i] += __shfl_xor(acc[i], m);
        }

        if (slot == 0) {
            const float dinv = rsqrtf(dcur);   // deg clamped >= 1 by setup
            v4f lo = {acc[0] * dinv, acc[1] * dinv, acc[2] * dinv, acc[3] * dinv};
            v4f hi = {acc[4] * dinv, acc[5] * dinv, acc[6] * dinv, acc[7] * dinv};
            char* po = (char*)out + (((unsigned)row) << 8) + (k << 5);
            __builtin_nontemporal_store(lo, reinterpret_cast<v4f*>(po));
            __builtin_nontemporal_store(hi, reinterpret_cast<v4f*>(po + 16));
        }

        if (npair >= npairs) break;
        pair = npair; row = nrow; start = nstart; end = nend; dcur = ndeg;
    }
}

// ---------------- fallback: fp32 gather (round-3 kernel) --------------------
__global__ __launch_bounds__(256) void gcn_csr_agg_f(
    const int* __restrict__ row_ptr,
    const int* __restrict__ col_idx,
    const float* __restrict__ feat,
    const float* __restrict__ deg,
    float* __restrict__ out,
    int n_nodes)
{
    const int gtid = blockIdx.x * blockDim.x + threadIdx.x;
    const int row  = gtid >> 6;
    if (row >= n_nodes) return;
    const int lane = threadIdx.x & 63;
    const int sub  = lane >> 4;
    const int fbyte = (lane & 15) << 4;

    const int start = row_ptr[row];
    const int end   = row_ptr[row + 1];
    const int last  = end - 1;
    const float dinv = rsqrtf(deg[row]);
    const char* fbase = (const char*)feat;

    v4f acc = {0.f, 0.f, 0.f, 0.f};

    for (int eb = start; eb < end; eb += 16) {
        int e[4]; int s[4]; float d[4]; v4f f[4];
#pragma unroll
        for (int u = 0; u < 4; ++u) {
            e[u] = eb + sub + 4 * u;
            const int c = min(e[u], last);
            s[u] = col_idx[c];
        }
#pragma unroll
        for (int u = 0; u < 4; ++u) {
            d[u] = deg[s[u]];
            const unsigned off = ((unsigned)s[u] << 8) + fbyte;
            f[u] = *reinterpret_cast<const v4f*>(fbase + off);
        }
#pragma unroll
        for (int u = 0; u < 4; ++u) {
            const float w = (e[u] <= last) ? dinv * rsqrtf(d[u]) : 0.f;
            acc += w * f[u];
        }
    }

    acc.x += __shfl_xor(acc.x, 16); acc.y += __shfl_xor(acc.y, 16);
    acc.z += __shfl_xor(acc.z, 16); acc.w += __shfl_xor(acc.w, 16);
    acc.x += __shfl_xor(acc.x, 32); acc.y += __shfl_xor(acc.y, 32);
    acc.z += __shfl_xor(acc.z, 32); acc.w += __shfl_xor(acc.w, 32);

    if (sub == 0) {
        v4f* po = reinterpret_cast<v4f*>((char*)out + ((unsigned)row << 8) + fbyte);
        __builtin_nontemporal_store(acc, po);
    }
}

extern "C" void kernel_launch(void* const* d_in, const int* in_sizes, int n_in,
                              void* d_out, int out_size, void* d_ws, size_t ws_size,
                              hipStream_t stream) {
    const int*   row_ptr = (const int*)d_in[0];
    const int*   col_idx = (const int*)d_in[1];
    const float* feat    = (const float*)d_in[2];
    const float* deg     = (const float*)d_in[3];
    float*       out     = (float*)d_out;

    const int n_nodes = in_sizes[0] - 1;
    const int n_edges = in_sizes[1];
    const int n_feat_elems = in_sizes[2];            // n_nodes * 64
    const size_t h_bytes = (size_t)(n_feat_elems + 64) * 2; // fp16 + zero row

    const int block = 256;

    if (ws_size >= h_bytes) {
        const int n4 = n_feat_elems >> 2;
        const int cgrid = (n4 + 16 + block - 1) / block;
        conv_fold<<<cgrid, block, 0, stream>>>(
            (const float4*)feat, deg, (uint2*)d_ws, n4);

        const int npairs = (n_nodes + 1) >> 1;
        const long long want_waves = npairs;              // one pair per wave min
        const int max_blocks = 2048;                      // 8 blocks/CU resident
        long long need_blocks = (want_waves * 64 + block - 1) / block;
        const int grid = (int)(need_blocks < max_blocks ? need_blocks : max_blocks);
        gcn_gather2p<<<grid, block, 0, stream>>>(
            row_ptr, col_idx, (const unsigned*)d_ws, deg, out, n_nodes, n_edges);
    } else {
        const long long threads = (long long)n_nodes * 64;
        const int grid  = (int)((threads + block - 1) / block);
        gcn_csr_agg_f<<<grid, block, 0, stream>>>(
            row_ptr, col_idx, feat, deg, out, n_nodes);
    }
}